// Round 16
// baseline (38700.406 us; speedup 1.0000x reference)
//
#include <hip/hip_runtime.h>
#include <cmath>

#define TDEC 250
#define EPS_A 1e-6f

// ---------------- block groups ----------------
#define NB_GIC  64   // 64 blocks: 4bg x 16jg
#define NB_GA   128  // 16 blocks: 4bg x 4jg
#define NB_WH1  144  // 8 blocks
#define NB_WH2  152  // 8 blocks
#define NBLK    160

// ---------------- ws float offsets (flags in words 0..8191) ----------------
// MEGA flag words: 0=ctx, 1=hatt, 2=h1, 3=h2. helpers: word 0.
#define B_CTX(p)  (8192   + (p)*49152)   // [64][768]
#define B_HATT(p) (106496 + (p)*16384)   // [64][256]
#define B_H1(p)   (139264 + (p)*16384)
#define B_H2(p)   (172032 + (p)*16384)
#define B_GIC(p)  (204800 + (p)*49152)   // [64][768]
#define B_GH(p)   (303104 + (p)*49152)
#define B_GH1(p)  (401408 + (p)*49152)
#define B_GH2(p)  (499712 + (p)*49152)
#define ZERO_END  598016
#define CVT_OFF   598016                 // bf16 weight region (u16)

// bf16 weight offsets (u16 units)
// k8-interleaved [K/8][N][8] region (MEGA GEMVs):
#define OP1    0u        // p1w  N=256 K=416(pad)
#define OP2    106496u   // p2w  N=128 K=256
#define OAWIP  139264u   // awi[:,768:896] N=768 K=128
#define ODW    237568u   // dWw  N=128 K=256
#define ODV    270336u   // dVw  N=168 K=128
#define OLW    291840u   // lw   N=256 K=1024
#define OG1I   553984u   // g1wi N=768 K=256
#define OG2I   750592u
#define OPR    947200u   // prw  N=400 K=256
// row-major region (helpers):
#define OAWI   1049600u  // awi  [768][896]
#define OAWH   1737728u  // awh  [768][256]
#define OG1H   1934336u
#define OG2H   2130944u
#define OENC   2327552u  // enc bf16 [64][512][768] (optional)
#define ENC_N  25165824u
// bytes needed for bf16-enc path:
#define NEED_BYTES (598016ull*4ull + (2327552ull + 25165824ull)*2ull)

struct Prior { float v[11]; };

struct KArgs {
  const float *enc;
  const float *p1w,*p1b,*p2w,*p2b;
  const float *awi,*abi,*awh,*abh;
  const float *dWw,*dWb,*dVw,*dFw,*dUw,*dTw,*dTb,*dvw;
  const float *lw,*lb;
  const float *g1wi,*g1bi,*g1wh,*g1bh;
  const float *g2wi,*g2bi,*g2wh,*g2bh;
  const float *prw,*prb;
  float* ws; float* dout;
  int ebf;
  Prior pr;
};

__device__ __forceinline__ float gld(const float* p) {
  return __uint_as_float(__hip_atomic_load((const unsigned*)p, __ATOMIC_RELAXED, __HIP_MEMORY_SCOPE_AGENT));
}
__device__ __forceinline__ void gst(float* p, float v) {
  __hip_atomic_store((unsigned*)p, __float_as_uint(v), __ATOMIC_RELAXED, __HIP_MEMORY_SCOPE_AGENT);
}
__device__ __forceinline__ float sigm(float x) { return 1.f / (1.f + expf(-x)); }
__device__ __forceinline__ float bfup(unsigned short u) { return __uint_as_float(((unsigned)u) << 16); }

// bf16-pair dot: one uint4 = 8 bf16 weights (k..k+7) vs 8 fp32 activations
__device__ __forceinline__ float dot8(uint4 w, float4 x0, float4 x1) {
  float a;
  a = __uint_as_float(w.x << 16) * x0.x;
  a = fmaf(__uint_as_float(w.x & 0xffff0000u), x0.y, a);
  a = fmaf(__uint_as_float(w.y << 16),         x0.z, a);
  a = fmaf(__uint_as_float(w.y & 0xffff0000u), x0.w, a);
  a = fmaf(__uint_as_float(w.z << 16),         x1.x, a);
  a = fmaf(__uint_as_float(w.z & 0xffff0000u), x1.y, a);
  a = fmaf(__uint_as_float(w.w << 16),         x1.z, a);
  a = fmaf(__uint_as_float(w.w & 0xffff0000u), x1.w, a);
  return a;
}

__global__ __launch_bounds__(256) void k_init(float* ws) {
  int idx = blockIdx.x * 256 + threadIdx.x;
  for (int i = idx; i < ZERO_END; i += gridDim.x * 256) ws[i] = 0.f;
}

// ---------------- fp32 -> bf16 weight conversion (row-major or k8-interleaved) ----
struct CvtSeg { const float* src; unsigned dst; unsigned N, K, KP, sstr, soff, mode; };
struct CvtArgs { CvtSeg s[13]; };
__global__ __launch_bounds__(256) void k_cvt(CvtArgs c, unsigned short* wb,
                                             const float* enc, int ebf) {
  for (int seg = 0; seg < 13; ++seg) {
    CvtSeg sg = c.s[seg];
    unsigned short* d = wb + sg.dst;
    unsigned tot = sg.N * sg.KP;
    for (unsigned i = blockIdx.x * 256 + threadIdx.x; i < tot; i += gridDim.x * 256) {
      if (sg.mode == 0) {
        unsigned u = __float_as_uint(sg.src[i]);
        d[i] = (unsigned short)((u + 0x7fffu + ((u >> 16) & 1u)) >> 16);
      } else {
        unsigned n = i / sg.KP, k = i - n * sg.KP;
        unsigned short v = 0;
        if (k < sg.K) {
          unsigned u = __float_as_uint(sg.src[(size_t)n * sg.sstr + sg.soff + k]);
          v = (unsigned short)((u + 0x7fffu + ((u >> 16) & 1u)) >> 16);
        }
        d[(k >> 3) * (sg.N * 8) + n * 8 + (k & 7)] = v;
      }
    }
  }
  if (ebf) {
    unsigned short* d = wb + OENC;
    for (unsigned i = blockIdx.x * 256 + threadIdx.x; i < ENC_N; i += gridDim.x * 256) {
      unsigned u = __float_as_uint(enc[i]);
      d[i] = (unsigned short)((u + 0x7fffu + ((u >> 16) & 1u)) >> 16);
    }
  }
}

__device__ __forceinline__ void postw(unsigned* fl, int word, unsigned v) {
  asm volatile("s_waitcnt vmcnt(0)" ::: "memory");
  __syncthreads();
  if (threadIdx.x == 0)
    __hip_atomic_store(&fl[blockIdx.x * 32 + word], v, __ATOMIC_RELAXED, __HIP_MEMORY_SCOPE_AGENT);
}
template <int SLP>
__device__ __forceinline__ void pollge(unsigned* fl, int line, int word, unsigned v) {
  while (__hip_atomic_load(&fl[line * 32 + word], __ATOMIC_RELAXED, __HIP_MEMORY_SCOPE_AGENT) < v)
    __builtin_amdgcn_s_sleep(SLP);
}

// ---------------- the persistent decoder ----------------
__global__ __launch_bounds__(1024, 1) void k_decode(KArgs A) {
  __shared__ __align__(16) float sm[16640];
  float* ws = A.ws;
  unsigned* fl = (unsigned*)ws;
  const unsigned short* wb = (const unsigned short*)(ws + CVT_OFF);
  const int blk = blockIdx.x;
  const int tid = threadIdx.x;

  if (blk < 64) {
    // ========== MEGA: one block per batch row, entire per-step chain; k8 GEMVs ==========
    const int b = blk, bg = b >> 4;
    float* alpha = sm;            // 512
    float* hattl = sm + 512;      // 256
    float* h1l   = sm + 768;      // 256
    float* h2l   = sm + 1024;     // 256
    float* fr    = sm + 1280;     // 416
    float* xcat  = sm + 1696;     // 1032 (ctx 768 | hatt 256)
    float* xl    = sm + 2728;     // 256
    float* x2l   = sm + 2984;     // 256
    float* x3l   = sm + 3240;     // 256
    float* sal   = sm + 3496;     // 544
    float* h1s   = sm + 4040;     // 256
    float* pre   = sm + 4296;     // 128
    float* sgi   = sm + 4424;     // 768
    float* sgh   = sm + 5192;     // 768
    float* t1    = sm + 5960;     // 128
    float* Gl    = sm + 6088;     // 176
    float* sdF   = sm + 6264;     // 176
    float* sdU   = sm + 6440;     // 1024
    float* sdT   = sm + 7464;     // 1024
    float* sdtb  = sm + 8488;     // 128
    float* sdv   = sm + 8616;     // 128
    float* es    = sm + 8744;     // 1024
    float* e     = sm + 9768;     // 512
    float* red   = sm + 10280;    // 16
    int*   wc    = (int*)(sm + 10296); // 8
    float* lv    = sm + 10304;    // 512
    short* li    = (short*)(sm + 10816); // 512 shorts
    float* pt    = sm + 11072;    // 1056 partials

    if (tid < 512) alpha[tid] = (tid == 0) ? 1.f : 0.f;
    if (tid < 256) { hattl[tid] = 0.f; h1l[tid] = 0.f; h2l[tid] = 0.f; xcat[768 + tid] = 0.f; }
    if (tid < 416) fr[tid] = 0.f;
    if (tid < 176) sdF[tid] = (tid < 168) ? A.dFw[tid] : 0.f;
    sdU[tid] = A.dUw[tid];
    sdT[tid] = A.dTw[tid];
    if (tid < 128) { sdtb[tid] = A.dTb[tid]; sdv[tid] = A.dvw[tid]; }
    __syncthreads();

    for (int t = 0; t < TDEC; ++t) {
      const int p = t & 1;
      // S0: alpha -> padded sal
      if (tid < 544) { int sg = tid - 10; sal[tid] = (sg >= 0 && sg < 512) ? alpha[sg] : 0.f; }
      __syncthreads();
      // S1: prenet L1  N=256 K=416, 4 parts x 13 groups
      {
        int part = tid >> 8, j = tid & 255;
        const float4* xr = (const float4*)fr;
        float a = 0.f;
#pragma unroll
        for (int g = 0; g < 13; ++g) {
          int gg = part * 13 + g;
          uint4 w = *(const uint4*)(wb + OP1 + (size_t)gg * 2048 + j * 8);
          a += dot8(w, xr[gg * 2], xr[gg * 2 + 1]);
        }
        pt[part * 260 + j] = a;
      }
      __syncthreads();
      if (tid < 256) h1s[tid] = fmaxf(pt[tid] + pt[260 + tid] + pt[520 + tid] + pt[780 + tid] + A.p1b[tid], 0.f);
      __syncthreads();
      // S2: prenet L2  N=128 K=256, 8 parts x 4 groups
      {
        int part = tid >> 7, j = tid & 127;
        const float4* xr = (const float4*)h1s;
        float a = 0.f;
#pragma unroll
        for (int g = 0; g < 4; ++g) {
          int gg = part * 4 + g;
          uint4 w = *(const uint4*)(wb + OP2 + (size_t)gg * 1024 + j * 8);
          a += dot8(w, xr[gg * 2], xr[gg * 2 + 1]);
        }
        pt[part * 132 + j] = a;
      }
      __syncthreads();
      if (tid < 128) {
        float a = A.p2b[tid];
#pragma unroll
        for (int q = 0; q < 8; ++q) a += pt[q * 132 + tid];
        pre[tid] = fmaxf(a, 0.f);
      }
      __syncthreads();
      // S3: gip = awi[:,768:] @ pre  (N=768 K=128) || poll GIC + GA
      float gipre = 0.f;
      if (tid < 768) {
        const float4* xr = (const float4*)pre;
        float a = 0.f;
#pragma unroll
        for (int g = 0; g < 16; ++g) {
          uint4 w = *(const uint4*)(wb + OAWIP + (size_t)g * 6144 + tid * 8);
          a += dot8(w, xr[g * 2], xr[g * 2 + 1]);
        }
        gipre = a;
      } else if (tid < 784) {
        pollge<1>(fl, NB_GIC + bg * 16 + (tid - 768), 0, (unsigned)(t + 1));
      } else if (tid < 788) {
        pollge<1>(fl, NB_GA + bg * 4 + (tid - 784), 0, (unsigned)(t + 1));
      }
      __syncthreads();
      // S4: gate pre-activations
      if (tid < 768) {
        sgi[tid] = gipre + gld(ws + B_GIC(p) + b * 768 + tid) + A.abi[tid];
        sgh[tid] = gld(ws + B_GH(p) + b * 768 + tid) + A.abh[tid];
      }
      __syncthreads();
      // S5: att-GRU combine -> hatt
      if (tid < 256) {
        float r = sigm(sgi[tid] + sgh[tid]);
        float z = sigm(sgi[256 + tid] + sgh[256 + tid]);
        float n = tanhf(sgi[512 + tid] + r * sgh[512 + tid]);
        float hnew = (1.f - z) * n + z * hattl[tid];
        hattl[tid] = hnew;
        xcat[768 + tid] = hnew;
        gst(ws + B_HATT(p) + b * 256 + tid, hnew);
      }
      postw(fl, 1, (unsigned)(t + 1));
      // S6: t1 = tanh(dW @ hatt + dWb)  N=128 K=256
      {
        int part = tid >> 7, j = tid & 127;
        const float4* xr = (const float4*)hattl;
        float a = 0.f;
#pragma unroll
        for (int g = 0; g < 4; ++g) {
          int gg = part * 4 + g;
          uint4 w = *(const uint4*)(wb + ODW + (size_t)gg * 1024 + j * 8);
          a += dot8(w, xr[gg * 2], xr[gg * 2 + 1]);
        }
        pt[part * 132 + j] = a;
      }
      __syncthreads();
      if (tid < 128) {
        float a = A.dWb[tid];
#pragma unroll
        for (int q = 0; q < 8; ++q) a += pt[q * 132 + tid];
        t1[tid] = tanhf(a);
      }
      __syncthreads();
      // S7: G = dV @ t1  N=168 K=128, 4 parts x 4 groups (672 threads)
      if (tid < 672) {
        int part = tid / 168, j = tid - part * 168;
        const float4* xr = (const float4*)t1;
        float a = 0.f;
#pragma unroll
        for (int g = 0; g < 4; ++g) {
          int gg = part * 4 + g;
          uint4 w = *(const uint4*)(wb + ODV + (size_t)gg * 1344 + j * 8);
          a += dot8(w, xr[gg * 2], xr[gg * 2 + 1]);
        }
        pt[part * 172 + j] = a;
      }
      __syncthreads();
      if (tid < 168) Gl[tid] = pt[tid] + pt[172 + tid] + pt[344 + tid] + pt[516 + tid];
      __syncthreads();
      // S8: static+dynamic conv fused with energy MLP
      {
        int sl = tid >> 1, half = tid & 1;
        float f0[8], g0[8];
#pragma unroll
        for (int q = 0; q < 8; ++q) {
          float fa = 0.f, ga = 0.f;
#pragma unroll
          for (int k = 0; k < 21; ++k) {
            float a = sal[sl + k];
            fa = fmaf(sdF[q * 21 + k], a, fa);
            ga = fmaf(Gl[q * 21 + k], a, ga);
          }
          f0[q] = fa; g0[q] = ga;
        }
        float acc = 0.f;
        for (int cc = half * 64; cc < half * 64 + 64; ++cc) {
          float a = sdtb[cc];
#pragma unroll
          for (int q = 0; q < 8; ++q)
            a = fmaf(sdU[cc * 8 + q], f0[q], fmaf(sdT[cc * 8 + q], g0[q], a));
          acc = fmaf(sdv[cc], tanhf(a), acc);
        }
        es[sl * 2 + half] = acc;
      }
      __syncthreads();
      // S9a: e = mlp + log(prior)
      if (tid < 512) {
        float pr = 0.f;
#pragma unroll
        for (int k = 0; k < 11; ++k) pr = fmaf(A.pr.v[k], sal[tid + k], pr);
        e[tid] = es[tid * 2] + es[tid * 2 + 1] + logf(fmaxf(pr, 1e-6f));
      }
      __syncthreads();
      // S9b: softmax + compaction + sparse ctx
      {
        int lane = tid & 63, wv = tid >> 6;
        float e0 = (tid < 512) ? e[tid] : -1e30f;
        float m = e0;
        for (int o = 32; o; o >>= 1) m = fmaxf(m, __shfl_xor(m, o));
        if (lane == 0) red[wv] = m;
        __syncthreads();
        m = red[0];
        for (int w = 1; w < 8; ++w) m = fmaxf(m, red[w]);
        float p0 = (tid < 512) ? expf(e0 - m) : 0.f;
        float s = p0;
        for (int o = 32; o; o >>= 1) s += __shfl_xor(s, o);
        __syncthreads();
        if (lane == 0) red[wv] = s;
        __syncthreads();
        float tot = red[0];
        for (int w = 1; w < 8; ++w) tot += red[w];
        float inv = 1.f / tot;
        float a0 = p0 * inv;
        if (tid < 512) alpha[tid] = a0;
        unsigned long long mk = __ballot(tid < 512 && a0 > EPS_A);
        if (lane == 0 && wv < 8) wc[wv] = (int)__popcll(mk);
        __syncthreads();
        int base = 0;
        for (int w = 0; w < wv && w < 8; ++w) base += wc[w];
        int n = 0;
        for (int w = 0; w < 8; ++w) n += wc[w];
        unsigned long long below = (1ull << lane) - 1ull;
        if (tid < 512 && a0 > EPS_A) {
          int pp = base + (int)__popcll(mk & below);
          li[pp] = (short)tid; lv[pp] = a0;
        }
        __syncthreads();
        if (tid < 768) {
          float acc0 = 0.f, acc1 = 0.f;
          if (A.ebf) {
            const unsigned short* encw = wb + OENC + (size_t)b * 512 * 768;
            int i = 0;
            for (; i + 8 <= n; i += 8) {
              acc0 = fmaf(lv[i],   bfup(encw[(size_t)li[i]   * 768 + tid]),
                     fmaf(lv[i+1], bfup(encw[(size_t)li[i+1] * 768 + tid]),
                     fmaf(lv[i+2], bfup(encw[(size_t)li[i+2] * 768 + tid]),
                     fmaf(lv[i+3], bfup(encw[(size_t)li[i+3] * 768 + tid]), acc0))));
              acc1 = fmaf(lv[i+4], bfup(encw[(size_t)li[i+4] * 768 + tid]),
                     fmaf(lv[i+5], bfup(encw[(size_t)li[i+5] * 768 + tid]),
                     fmaf(lv[i+6], bfup(encw[(size_t)li[i+6] * 768 + tid]),
                     fmaf(lv[i+7], bfup(encw[(size_t)li[i+7] * 768 + tid]), acc1))));
            }
            for (; i < n; ++i) acc0 = fmaf(lv[i], bfup(encw[(size_t)li[i] * 768 + tid]), acc0);
          } else {
            const float* encb = A.enc + (size_t)b * 512 * 768;
            int i = 0;
            for (; i + 8 <= n; i += 8) {
              acc0 = fmaf(lv[i],   encb[(size_t)li[i]   * 768 + tid],
                     fmaf(lv[i+1], encb[(size_t)li[i+1] * 768 + tid],
                     fmaf(lv[i+2], encb[(size_t)li[i+2] * 768 + tid],
                     fmaf(lv[i+3], encb[(size_t)li[i+3] * 768 + tid], acc0))));
              acc1 = fmaf(lv[i+4], encb[(size_t)li[i+4] * 768 + tid],
                     fmaf(lv[i+5], encb[(size_t)li[i+5] * 768 + tid],
                     fmaf(lv[i+6], encb[(size_t)li[i+6] * 768 + tid],
                     fmaf(lv[i+7], encb[(size_t)li[i+7] * 768 + tid], acc1))));
            }
            for (; i < n; ++i) acc0 = fmaf(lv[i], encb[(size_t)li[i] * 768 + tid], acc0);
          }
          float acc = acc0 + acc1;
          xcat[tid] = acc;
          gst(ws + B_CTX(p) + b * 768 + tid, acc);
        }
      }
      postw(fl, 0, (unsigned)(t + 1));
      // S10: x = lw @ [ctx; hatt] + lb  N=256 K=1024, 4 parts x 32 groups
      {
        int part = tid >> 8, j = tid & 255;
        const float4* xr = (const float4*)xcat;
        float a = 0.f;
#pragma unroll 16
        for (int g = 0; g < 32; ++g) {
          int gg = part * 32 + g;
          uint4 w = *(const uint4*)(wb + OLW + (size_t)gg * 2048 + j * 8);
          a += dot8(w, xr[gg * 2], xr[gg * 2 + 1]);
        }
        pt[part * 260 + j] = a;
      }
      __syncthreads();
      if (tid < 256) xl[tid] = pt[tid] + pt[260 + tid] + pt[520 + tid] + pt[780 + tid] + A.lb[tid];
      __syncthreads();
      // S11: GRU1 (g1wi k8; gh1 from WH1 helper)
      {
        float giv = 0.f;
        if (tid < 768) {
          const float4* xr = (const float4*)xl;
          float a = 0.f;
#pragma unroll 16
          for (int g = 0; g < 32; ++g) {
            uint4 w = *(const uint4*)(wb + OG1I + (size_t)g * 6144 + tid * 8);
            a += dot8(w, xr[g * 2], xr[g * 2 + 1]);
          }
          giv = a;
        } else if (tid < 776) {
          pollge<1>(fl, NB_WH1 + (tid - 768), 0, (unsigned)(t + 1));
        }
        __syncthreads();
        if (tid < 768) {
          sgi[tid] = giv + A.g1bi[tid];
          sgh[tid] = gld(ws + B_GH1(p) + b * 768 + tid);   // helper added g1bh
        }
        __syncthreads();
        if (tid < 256) {
          float r = sigm(sgi[tid] + sgh[tid]);
          float z = sigm(sgi[256 + tid] + sgh[256 + tid]);
          float n = tanhf(sgi[512 + tid] + r * sgh[512 + tid]);
          float hnew = (1.f - z) * n + z * h1l[tid];
          h1l[tid] = hnew;
          gst(ws + B_H1(p) + b * 256 + tid, hnew);
          x2l[tid] = xl[tid] + hnew;
        }
        postw(fl, 2, (unsigned)(t + 1));
      }
      // S12: GRU2
      {
        float giv = 0.f;
        if (tid < 768) {
          const float4* xr = (const float4*)x2l;
          float a = 0.f;
#pragma unroll 16
          for (int g = 0; g < 32; ++g) {
            uint4 w = *(const uint4*)(wb + OG2I + (size_t)g * 6144 + tid * 8);
            a += dot8(w, xr[g * 2], xr[g * 2 + 1]);
          }
          giv = a;
        } else if (tid < 776) {
          pollge<1>(fl, NB_WH2 + (tid - 768), 0, (unsigned)(t + 1));
        }
        __syncthreads();
        if (tid < 768) {
          sgi[tid] = giv + A.g2bi[tid];
          sgh[tid] = gld(ws + B_GH2(p) + b * 768 + tid);
        }
        __syncthreads();
        if (tid < 256) {
          float r = sigm(sgi[tid] + sgh[tid]);
          float z = sigm(sgi[256 + tid] + sgh[256 + tid]);
          float n = tanhf(sgi[512 + tid] + r * sgh[512 + tid]);
          float hnew = (1.f - z) * n + z * h2l[tid];
          h2l[tid] = hnew;
          gst(ws + B_H2(p) + b * 256 + tid, hnew);
          x3l[tid] = x2l[tid] + hnew;
        }
        postw(fl, 3, (unsigned)(t + 1));
      }
      // S13: proj  N=400 K=256, 2 parts x 16 groups (800 threads)
      if (tid < 800) {
        int part = tid >= 400 ? 1 : 0, j = tid - part * 400;
        const float4* xr = (const float4*)x3l;
        float a = 0.f;
#pragma unroll
        for (int g = 0; g < 16; ++g) {
          int gg = part * 16 + g;
          uint4 w = *(const uint4*)(wb + OPR + (size_t)gg * 3200 + j * 8);
          a += dot8(w, xr[gg * 2], xr[gg * 2 + 1]);
        }
        pt[part * 404 + j] = a;
      }
      __syncthreads();
      if (tid < 400) {
        float v = pt[tid] + pt[404 + tid] + A.prb[tid];
        fr[tid] = v;
        gst(A.dout + (size_t)b * 100000 + (tid / 5) * 1250 + t * 5 + (tid % 5), v);
      }
      __syncthreads();
    }
  } else if (blk < NB_GA) {
    // ---- GIC: gic(t) = awi[:, :768] @ ctx(t-1)  (shadow, row-major) ----
    int rb = blk - NB_GIC, bg = rb >> 4, jg = rb & 15;
    int B = bg * 16, R0 = jg * 48;
    float* cl = sm;  // [16][772]
    for (int t = 0; t < TDEC; ++t) {
      const int p = t & 1;
      if (tid < 16) pollge<4>(fl, bg * 16 + tid, 0, (unsigned)t);
      __syncthreads();
      for (int idx = tid; idx < 12288; idx += 1024) {
        int bb = idx / 768, k = idx - bb * 768;
        cl[bb * 772 + k] = gld(ws + B_CTX(p ^ 1) + (B + bb) * 768 + k);
      }
      __syncthreads();
      if (tid < 768) {
        int rr = tid >> 4, bb = tid & 15;
        int row = R0 + rr;
        const uint4* wr = (const uint4*)(wb + OAWI + (size_t)row * 896);
        const float4* xr = (const float4*)(cl + bb * 772);
        float a = 0.f;
#pragma unroll 16
        for (int k4 = 0; k4 < 96; ++k4) a += dot8(wr[k4], xr[2*k4], xr[2*k4+1]);
        gst(ws + B_GIC(p) + (B + bb) * 768 + row, a);
      }
      postw(fl, 0, (unsigned)(t + 1));
    }
  } else if (blk < NB_WH1) {
    // ---- GA: gh(t) = awh @ hatt(t-1)  (shadow) ----
    int rb = blk - NB_GA, bg = rb >> 2, jg = rb & 3;
    int B = bg * 16, R0 = jg * 192;
    float* hl = sm;  // [16][260]
    for (int t = 0; t < TDEC; ++t) {
      const int p = t & 1;
      if (tid < 16) pollge<4>(fl, bg * 16 + tid, 1, (unsigned)t);
      __syncthreads();
      for (int idx = tid; idx < 4096; idx += 1024) {
        int bb = idx >> 8, k = idx & 255;
        hl[bb * 260 + k] = gld(ws + B_HATT(p ^ 1) + (B + bb) * 256 + k);
      }
      __syncthreads();
#pragma unroll
      for (int pass = 0; pass < 3; ++pass) {
        int rr = pass * 64 + (tid >> 4), bb = tid & 15;
        int row = R0 + rr;
        const uint4* wr = (const uint4*)(wb + OAWH + (size_t)row * 256);
        const float4* xr = (const float4*)(hl + bb * 260);
        float a = 0.f;
#pragma unroll 16
        for (int k4 = 0; k4 < 32; ++k4) a += dot8(wr[k4], xr[2*k4], xr[2*k4+1]);
        gst(ws + B_GH(p) + (B + bb) * 768 + row, a);
      }
      postw(fl, 0, (unsigned)(t + 1));
    }
  } else {
    // ---- WH1/WH2: gh{1,2}(t) = g{1,2}wh @ h{1,2}(t-1), all 64 b  (shadow) ----
    const int isW2 = (blk >= NB_WH2);
    const int w = blk - (isW2 ? NB_WH2 : NB_WH1);
    const unsigned OW = isW2 ? OG2H : OG1H;
    const float* bh = isW2 ? A.g2bh : A.g1bh;
    const int hOff0  = isW2 ? B_H2(0)  : B_H1(0);
    const int ghOff0 = isW2 ? B_GH2(0) : B_GH1(0);
    const int word = isW2 ? 3 : 2;
    const int R0 = w * 96;
    float* hl = sm;  // [64][260]
    for (int t = 0; t < TDEC; ++t) {
      const int p = t & 1;
      if (tid < 64) pollge<4>(fl, tid, word, (unsigned)t);
      __syncthreads();
      for (int idx = tid; idx < 16384; idx += 1024) {
        int bb = idx >> 8, k = idx & 255;
        hl[bb * 260 + k] = gld(ws + hOff0 + (p ^ 1) * 16384 + bb * 256 + k);
      }
      __syncthreads();
#pragma unroll
      for (int pass = 0; pass < 6; ++pass) {
        int o = pass * 1024 + tid;
        int bb = o & 63, lr = o >> 6;
        int row = R0 + lr;
        const uint4* wr = (const uint4*)(wb + OW + (size_t)row * 256);
        const float4* xr = (const float4*)(hl + bb * 260);
        float a = 0.f;
#pragma unroll 16
        for (int k4 = 0; k4 < 32; ++k4) a += dot8(wr[k4], xr[2*k4], xr[2*k4+1]);
        gst(ws + ghOff0 + p * 49152 + bb * 768 + row, a + bh[row]);
      }
      postw(fl, 0, (unsigned)(t + 1));
    }
  }
}

// ---------------- host ----------------
extern "C" void kernel_launch(void* const* d_in, const int* in_sizes, int n_in,
                              void* d_out, int out_size, void* d_ws, size_t ws_size,
                              hipStream_t stream) {
  (void)in_sizes; (void)n_in; (void)out_size;
  KArgs A;
  A.enc  = (const float*)d_in[0];
  A.p1w  = (const float*)d_in[1];  A.p1b  = (const float*)d_in[2];
  A.p2w  = (const float*)d_in[3];  A.p2b  = (const float*)d_in[4];
  A.awi  = (const float*)d_in[5];  A.abi  = (const float*)d_in[6];
  A.awh  = (const float*)d_in[7];  A.abh  = (const float*)d_in[8];
  A.dWw  = (const float*)d_in[9];  A.dWb  = (const float*)d_in[10];
  A.dVw  = (const float*)d_in[11]; A.dFw  = (const float*)d_in[12];
  A.dUw  = (const float*)d_in[13]; A.dTw  = (const float*)d_in[14];
  A.dTb  = (const float*)d_in[15]; A.dvw  = (const float*)d_in[16];
  A.lw   = (const float*)d_in[17]; A.lb   = (const float*)d_in[18];
  A.g1wi = (const float*)d_in[19]; A.g1bi = (const float*)d_in[20];
  A.g1wh = (const float*)d_in[21]; A.g1bh = (const float*)d_in[22];
  A.g2wi = (const float*)d_in[23]; A.g2bi = (const float*)d_in[24];
  A.g2wh = (const float*)d_in[25]; A.g2bh = (const float*)d_in[26];
  A.prw  = (const float*)d_in[27]; A.prb  = (const float*)d_in[28];
  A.ws   = (float*)d_ws;
  A.dout = (float*)d_out;
  A.ebf  = (ws_size >= (size_t)NEED_BYTES) ? 1 : 0;

  // beta-binomial prior pmf (n=10, a=0.1, b=0.9), flipped
  {
    double aP = 0.1, bP = 0.9;
    double logB0 = lgamma(aP) + lgamma(bP) - lgamma(aP + bP);
    double pm[11];
    for (int k = 0; k <= 10; ++k) {
      double logC = lgamma(11.0) - lgamma(k + 1.0) - lgamma(11.0 - k);
      double logBt = lgamma(k + aP) + lgamma(10.0 - k + bP) - lgamma(10.0 + aP + bP);
      pm[k] = exp(logC + logBt - logB0);
    }
    for (int k = 0; k < 11; ++k) A.pr.v[k] = (float)pm[10 - k];
  }

  CvtArgs C;
  // k8-interleaved (mode 1): {src, dst, N, K, KP, sstr, soff, mode}
  C.s[0]  = {A.p1w,  OP1,   256, 400, 416, 400, 0, 1};
  C.s[1]  = {A.p2w,  OP2,   128, 256, 256, 256, 0, 1};
  C.s[2]  = {A.awi,  OAWIP, 768, 128, 128, 896, 768, 1};
  C.s[3]  = {A.dWw,  ODW,   128, 256, 256, 256, 0, 1};
  C.s[4]  = {A.dVw,  ODV,   168, 128, 128, 128, 0, 1};
  C.s[5]  = {A.lw,   OLW,   256, 1024, 1024, 1024, 0, 1};
  C.s[6]  = {A.g1wi, OG1I,  768, 256, 256, 256, 0, 1};
  C.s[7]  = {A.g2wi, OG2I,  768, 256, 256, 256, 0, 1};
  C.s[8]  = {A.prw,  OPR,   400, 256, 256, 256, 0, 1};
  // row-major (mode 0): N*KP = element count
  C.s[9]  = {A.awi,  OAWI,  768, 896, 896, 896, 0, 0};
  C.s[10] = {A.awh,  OAWH,  768, 256, 256, 256, 0, 0};
  C.s[11] = {A.g1wh, OG1H,  768, 256, 256, 256, 0, 0};
  C.s[12] = {A.g2wh, OG2H,  768, 256, 256, 256, 0, 0};

  k_init<<<256, 256, 0, stream>>>((float*)d_ws);
  k_cvt<<<256, 256, 0, stream>>>(C, (unsigned short*)((float*)d_ws + CVT_OFF), A.enc, A.ebf);
  k_decode<<<NBLK, 1024, 0, stream>>>(A);
}

// Round 17
// 31660.349 us; speedup vs baseline: 1.2224x; 1.2224x over previous
//
#include <hip/hip_runtime.h>
#include <cmath>

#define TDEC 250
#define EPS_A 1e-6f

// ---------------- block groups ----------------
#define NB_GIC  64   // 64 blocks: 4bg x 16jg
#define NB_GA   128  // 16 blocks: 4bg x 4jg
#define NB_WH1  144  // 8 blocks
#define NB_WH2  152  // 8 blocks
#define NB_PART 160  // 64 partner blocks (one per b)
#define NBLK    224

// ---------------- ws float offsets (flags in words 0..8191) ----------------
// MEGA flag words: 0=ctx, 1=hatt, 2=h1lo+x2lo, 3=h2lo+x3lo, 4=xlo.
// partner (line 160+b) words: 0=xh, 1=h1hi+x2hi, 2=h2hi+x3hi, 3=fr_hi.
#define B_CTX(p)  (8192   + (p)*49152)   // [64][768]
#define B_HATT(p) (106496 + (p)*16384)   // [64][256]
#define B_H1(p)   (139264 + (p)*16384)
#define B_H2(p)   (172032 + (p)*16384)
#define B_GIC(p)  (204800 + (p)*49152)   // [64][768]
#define B_GH(p)   (303104 + (p)*49152)
#define B_GH1(p)  (401408 + (p)*49152)
#define B_GH2(p)  (499712 + (p)*49152)
#define B_XLO(p)  (598016 + (p)*8192)    // [64][128]
#define B_XH(p)   (614400 + (p)*8192)
#define B_X2LO(p) (630784 + (p)*8192)
#define B_X2H(p)  (647168 + (p)*8192)
#define B_X3LO(p) (663552 + (p)*8192)
#define B_X3H(p)  (679936 + (p)*8192)
#define B_FRH(p)  (696320 + (p)*13312)   // [64][208]
#define ZERO_END  722944
#define CVT_OFF   722944                 // bf16 weight region (u16)

// bf16 weight offsets (u16 units)
// k8-interleaved [K/8][N][8] region (MEGA GEMVs):
#define OP1    0u        // p1w  N=256 K=416(pad)
#define OP2    106496u   // p2w  N=128 K=256
#define OAWIP  139264u   // awi[:,768:896] N=768 K=128
#define ODW    237568u   // dWw  N=128 K=256
#define ODV    270336u   // dVw  N=168 K=128
#define OLW    291840u   // lw   N=256 K=1024
#define OG1I   553984u   // g1wi N=768 K=256
#define OG2I   750592u
#define OPR    947200u   // prw  N=400 K=256
// row-major region (helpers):
#define OAWI   1049600u  // awi  [768][896]
#define OAWH   1737728u  // awh  [768][256]
#define OG1H   1934336u
#define OG2H   2130944u

struct Prior { float v[11]; };

struct KArgs {
  const float *enc;
  const float *p1w,*p1b,*p2w,*p2b;
  const float *awi,*abi,*awh,*abh;
  const float *dWw,*dWb,*dVw,*dFw,*dUw,*dTw,*dTb,*dvw;
  const float *lw,*lb;
  const float *g1wi,*g1bi,*g1wh,*g1bh;
  const float *g2wi,*g2bi,*g2wh,*g2bh;
  const float *prw,*prb;
  float* ws; float* dout;
  Prior pr;
};

__device__ __forceinline__ float gld(const float* p) {
  return __uint_as_float(__hip_atomic_load((const unsigned*)p, __ATOMIC_RELAXED, __HIP_MEMORY_SCOPE_AGENT));
}
__device__ __forceinline__ void gst(float* p, float v) {
  __hip_atomic_store((unsigned*)p, __float_as_uint(v), __ATOMIC_RELAXED, __HIP_MEMORY_SCOPE_AGENT);
}
__device__ __forceinline__ float sigm(float x) { return 1.f / (1.f + expf(-x)); }

// bf16-pair dot: one uint4 = 8 bf16 weights (k..k+7) vs 8 fp32 activations
__device__ __forceinline__ float dot8(uint4 w, float4 x0, float4 x1) {
  float a;
  a = __uint_as_float(w.x << 16) * x0.x;
  a = fmaf(__uint_as_float(w.x & 0xffff0000u), x0.y, a);
  a = fmaf(__uint_as_float(w.y << 16),         x0.z, a);
  a = fmaf(__uint_as_float(w.y & 0xffff0000u), x0.w, a);
  a = fmaf(__uint_as_float(w.z << 16),         x1.x, a);
  a = fmaf(__uint_as_float(w.z & 0xffff0000u), x1.y, a);
  a = fmaf(__uint_as_float(w.w << 16),         x1.z, a);
  a = fmaf(__uint_as_float(w.w & 0xffff0000u), x1.w, a);
  return a;
}

__global__ __launch_bounds__(256) void k_init(float* ws) {
  int idx = blockIdx.x * 256 + threadIdx.x;
  for (int i = idx; i < ZERO_END; i += gridDim.x * 256) ws[i] = 0.f;
}

// ---------------- fp32 -> bf16 weight conversion (row-major or k8-interleaved) ----
struct CvtSeg { const float* src; unsigned dst; unsigned N, K, KP, sstr, soff, mode; };
struct CvtArgs { CvtSeg s[13]; };
__global__ __launch_bounds__(256) void k_cvt(CvtArgs c, unsigned short* wb) {
  for (int seg = 0; seg < 13; ++seg) {
    CvtSeg sg = c.s[seg];
    unsigned short* d = wb + sg.dst;
    unsigned tot = sg.N * sg.KP;
    for (unsigned i = blockIdx.x * 256 + threadIdx.x; i < tot; i += gridDim.x * 256) {
      if (sg.mode == 0) {
        unsigned u = __float_as_uint(sg.src[i]);
        d[i] = (unsigned short)((u + 0x7fffu + ((u >> 16) & 1u)) >> 16);
      } else {
        unsigned n = i / sg.KP, k = i - n * sg.KP;
        unsigned short v = 0;
        if (k < sg.K) {
          unsigned u = __float_as_uint(sg.src[(size_t)n * sg.sstr + sg.soff + k]);
          v = (unsigned short)((u + 0x7fffu + ((u >> 16) & 1u)) >> 16);
        }
        d[(k >> 3) * (sg.N * 8) + n * 8 + (k & 7)] = v;
      }
    }
  }
}

__device__ __forceinline__ void postw(unsigned* fl, int word, unsigned v) {
  asm volatile("s_waitcnt vmcnt(0)" ::: "memory");
  __syncthreads();
  if (threadIdx.x == 0)
    __hip_atomic_store(&fl[blockIdx.x * 32 + word], v, __ATOMIC_RELAXED, __HIP_MEMORY_SCOPE_AGENT);
}
template <int SLP>
__device__ __forceinline__ void pollge(unsigned* fl, int line, int word, unsigned v) {
  while (__hip_atomic_load(&fl[line * 32 + word], __ATOMIC_RELAXED, __HIP_MEMORY_SCOPE_AGENT) < v)
    __builtin_amdgcn_s_sleep(SLP);
}

// ---------------- the persistent decoder ----------------
__global__ __launch_bounds__(1024, 1) void k_decode(KArgs A) {
  __shared__ __align__(16) float sm[16640];
  float* ws = A.ws;
  unsigned* fl = (unsigned*)ws;
  const unsigned short* wb = (const unsigned short*)(ws + CVT_OFF);
  const int blk = blockIdx.x;
  const int tid = threadIdx.x;

  if (blk < 64) {
    // ========== MEGA: attention core + low halves of S10-S13 ==========
    const int b = blk, bg = b >> 4;
    float* alpha = sm;            // 512
    float* hattl = sm + 512;      // 256
    float* h1l   = sm + 768;      // 128 (low half)
    float* h2l   = sm + 1024;     // 128
    float* fr    = sm + 1280;     // 416
    float* xcat  = sm + 1696;     // 1032 (ctx 768 | hatt 256)
    float* xl    = sm + 2728;     // 256
    float* x2l   = sm + 2984;     // 256
    float* x3l   = sm + 3240;     // 256
    float* sal   = sm + 3496;     // 544
    float* h1s   = sm + 4040;     // 256
    float* pre   = sm + 4296;     // 128
    float* sgi   = sm + 4424;     // 768
    float* sgh   = sm + 5192;     // 768
    float* t1    = sm + 5960;     // 128
    float* Gl    = sm + 6088;     // 176
    float* sdF   = sm + 6264;     // 176
    float* sdU   = sm + 6440;     // 1024
    float* sdT   = sm + 7464;     // 1024
    float* sdtb  = sm + 8488;     // 128
    float* sdv   = sm + 8616;     // 128
    float* es    = sm + 8744;     // 1024
    float* e     = sm + 9768;     // 512
    float* red   = sm + 10280;    // 16
    int*   wc    = (int*)(sm + 10296); // 8
    float* lv    = sm + 10304;    // 512
    short* li    = (short*)(sm + 10816); // 512 shorts
    float* pt    = sm + 11072;    // 1056 partials

    if (tid < 512) alpha[tid] = (tid == 0) ? 1.f : 0.f;
    if (tid < 256) { hattl[tid] = 0.f; xcat[768 + tid] = 0.f; }
    if (tid < 128) { h1l[tid] = 0.f; h2l[tid] = 0.f; }
    if (tid < 416) fr[tid] = 0.f;
    if (tid < 176) sdF[tid] = (tid < 168) ? A.dFw[tid] : 0.f;
    sdU[tid] = A.dUw[tid];
    sdT[tid] = A.dTw[tid];
    if (tid < 128) { sdtb[tid] = A.dTb[tid]; sdv[tid] = A.dvw[tid]; }
    __syncthreads();

    for (int t = 0; t < TDEC; ++t) {
      const int p = t & 1;
      // S0: alpha -> padded sal; poll fr_hi(t) and read it
      if (tid < 544) { int sg = tid - 10; sal[tid] = (sg >= 0 && sg < 512) ? alpha[sg] : 0.f; }
      else if (tid == 544) pollge<1>(fl, NB_PART + b, 3, (unsigned)t);
      __syncthreads();
      if (tid >= 200 && tid < 400) fr[tid] = gld(ws + B_FRH(p) + b * 208 + (tid - 200));
      __syncthreads();
      // S1: prenet L1  N=256 K=416, 4 parts x 13 groups
      {
        int part = tid >> 8, j = tid & 255;
        const float4* xr = (const float4*)fr;
        float a = 0.f;
#pragma unroll
        for (int g = 0; g < 13; ++g) {
          int gg = part * 13 + g;
          uint4 w = *(const uint4*)(wb + OP1 + (size_t)gg * 2048 + j * 8);
          a += dot8(w, xr[gg * 2], xr[gg * 2 + 1]);
        }
        pt[part * 260 + j] = a;
      }
      __syncthreads();
      if (tid < 256) h1s[tid] = fmaxf(pt[tid] + pt[260 + tid] + pt[520 + tid] + pt[780 + tid] + A.p1b[tid], 0.f);
      __syncthreads();
      // S2: prenet L2  N=128 K=256, 8 parts x 4 groups
      {
        int part = tid >> 7, j = tid & 127;
        const float4* xr = (const float4*)h1s;
        float a = 0.f;
#pragma unroll
        for (int g = 0; g < 4; ++g) {
          int gg = part * 4 + g;
          uint4 w = *(const uint4*)(wb + OP2 + (size_t)gg * 1024 + j * 8);
          a += dot8(w, xr[gg * 2], xr[gg * 2 + 1]);
        }
        pt[part * 132 + j] = a;
      }
      __syncthreads();
      if (tid < 128) {
        float a = A.p2b[tid];
#pragma unroll
        for (int q = 0; q < 8; ++q) a += pt[q * 132 + tid];
        pre[tid] = fmaxf(a, 0.f);
      }
      __syncthreads();
      // S3: gip = awi[:,768:] @ pre || poll GIC + GA
      float gipre = 0.f;
      if (tid < 768) {
        const float4* xr = (const float4*)pre;
        float a = 0.f;
#pragma unroll
        for (int g = 0; g < 16; ++g) {
          uint4 w = *(const uint4*)(wb + OAWIP + (size_t)g * 6144 + tid * 8);
          a += dot8(w, xr[g * 2], xr[g * 2 + 1]);
        }
        gipre = a;
      } else if (tid < 784) {
        pollge<1>(fl, NB_GIC + bg * 16 + (tid - 768), 0, (unsigned)(t + 1));
      } else if (tid < 788) {
        pollge<1>(fl, NB_GA + bg * 4 + (tid - 784), 0, (unsigned)(t + 1));
      }
      __syncthreads();
      // S4: gate pre-activations
      if (tid < 768) {
        sgi[tid] = gipre + gld(ws + B_GIC(p) + b * 768 + tid) + A.abi[tid];
        sgh[tid] = gld(ws + B_GH(p) + b * 768 + tid) + A.abh[tid];
      }
      __syncthreads();
      // S5: att-GRU combine -> hatt
      if (tid < 256) {
        float r = sigm(sgi[tid] + sgh[tid]);
        float z = sigm(sgi[256 + tid] + sgh[256 + tid]);
        float n = tanhf(sgi[512 + tid] + r * sgh[512 + tid]);
        float hnew = (1.f - z) * n + z * hattl[tid];
        hattl[tid] = hnew;
        xcat[768 + tid] = hnew;
        gst(ws + B_HATT(p) + b * 256 + tid, hnew);
      }
      postw(fl, 1, (unsigned)(t + 1));
      // S6: t1 = tanh(dW @ hatt + dWb)
      {
        int part = tid >> 7, j = tid & 127;
        const float4* xr = (const float4*)hattl;
        float a = 0.f;
#pragma unroll
        for (int g = 0; g < 4; ++g) {
          int gg = part * 4 + g;
          uint4 w = *(const uint4*)(wb + ODW + (size_t)gg * 1024 + j * 8);
          a += dot8(w, xr[gg * 2], xr[gg * 2 + 1]);
        }
        pt[part * 132 + j] = a;
      }
      __syncthreads();
      if (tid < 128) {
        float a = A.dWb[tid];
#pragma unroll
        for (int q = 0; q < 8; ++q) a += pt[q * 132 + tid];
        t1[tid] = tanhf(a);
      }
      __syncthreads();
      // S7: G = dV @ t1
      if (tid < 672) {
        int part = tid / 168, j = tid - part * 168;
        const float4* xr = (const float4*)t1;
        float a = 0.f;
#pragma unroll
        for (int g = 0; g < 4; ++g) {
          int gg = part * 4 + g;
          uint4 w = *(const uint4*)(wb + ODV + (size_t)gg * 1344 + j * 8);
          a += dot8(w, xr[gg * 2], xr[gg * 2 + 1]);
        }
        pt[part * 172 + j] = a;
      }
      __syncthreads();
      if (tid < 168) Gl[tid] = pt[tid] + pt[172 + tid] + pt[344 + tid] + pt[516 + tid];
      __syncthreads();
      // S8: static+dynamic conv fused with energy MLP
      {
        int sl = tid >> 1, half = tid & 1;
        float f0[8], g0[8];
#pragma unroll
        for (int q = 0; q < 8; ++q) {
          float fa = 0.f, ga = 0.f;
#pragma unroll
          for (int k = 0; k < 21; ++k) {
            float a = sal[sl + k];
            fa = fmaf(sdF[q * 21 + k], a, fa);
            ga = fmaf(Gl[q * 21 + k], a, ga);
          }
          f0[q] = fa; g0[q] = ga;
        }
        float acc = 0.f;
        for (int cc = half * 64; cc < half * 64 + 64; ++cc) {
          float a = sdtb[cc];
#pragma unroll
          for (int q = 0; q < 8; ++q)
            a = fmaf(sdU[cc * 8 + q], f0[q], fmaf(sdT[cc * 8 + q], g0[q], a));
          acc = fmaf(sdv[cc], tanhf(a), acc);
        }
        es[sl * 2 + half] = acc;
      }
      __syncthreads();
      // S9a: e = mlp + log(prior)
      if (tid < 512) {
        float pr = 0.f;
#pragma unroll
        for (int k = 0; k < 11; ++k) pr = fmaf(A.pr.v[k], sal[tid + k], pr);
        e[tid] = es[tid * 2] + es[tid * 2 + 1] + logf(fmaxf(pr, 1e-6f));
      }
      __syncthreads();
      // S9b: softmax + compaction + sparse ctx (cached fp32 enc)
      {
        int lane = tid & 63, wv = tid >> 6;
        float e0 = (tid < 512) ? e[tid] : -1e30f;
        float m = e0;
        for (int o = 32; o; o >>= 1) m = fmaxf(m, __shfl_xor(m, o));
        if (lane == 0) red[wv] = m;
        __syncthreads();
        m = red[0];
        for (int w = 1; w < 8; ++w) m = fmaxf(m, red[w]);
        float p0 = (tid < 512) ? expf(e0 - m) : 0.f;
        float s = p0;
        for (int o = 32; o; o >>= 1) s += __shfl_xor(s, o);
        __syncthreads();
        if (lane == 0) red[wv] = s;
        __syncthreads();
        float tot = red[0];
        for (int w = 1; w < 8; ++w) tot += red[w];
        float inv = 1.f / tot;
        float a0 = p0 * inv;
        if (tid < 512) alpha[tid] = a0;
        unsigned long long mk = __ballot(tid < 512 && a0 > EPS_A);
        if (lane == 0 && wv < 8) wc[wv] = (int)__popcll(mk);
        __syncthreads();
        int base = 0;
        for (int w = 0; w < wv && w < 8; ++w) base += wc[w];
        int n = 0;
        for (int w = 0; w < 8; ++w) n += wc[w];
        unsigned long long below = (1ull << lane) - 1ull;
        if (tid < 512 && a0 > EPS_A) {
          int pp = base + (int)__popcll(mk & below);
          li[pp] = (short)tid; lv[pp] = a0;
        }
        __syncthreads();
        const float* encb = A.enc + (size_t)b * 512 * 768;
        if (tid < 768) {
          float acc0 = 0.f, acc1 = 0.f;
          int i = 0;
          for (; i + 8 <= n; i += 8) {
            acc0 = fmaf(lv[i],   encb[(size_t)li[i]   * 768 + tid],
                   fmaf(lv[i+1], encb[(size_t)li[i+1] * 768 + tid],
                   fmaf(lv[i+2], encb[(size_t)li[i+2] * 768 + tid],
                   fmaf(lv[i+3], encb[(size_t)li[i+3] * 768 + tid], acc0))));
            acc1 = fmaf(lv[i+4], encb[(size_t)li[i+4] * 768 + tid],
                   fmaf(lv[i+5], encb[(size_t)li[i+5] * 768 + tid],
                   fmaf(lv[i+6], encb[(size_t)li[i+6] * 768 + tid],
                   fmaf(lv[i+7], encb[(size_t)li[i+7] * 768 + tid], acc1))));
          }
          for (; i < n; ++i) acc0 = fmaf(lv[i], encb[(size_t)li[i] * 768 + tid], acc0);
          float acc = acc0 + acc1;
          xcat[tid] = acc;
          gst(ws + B_CTX(p) + b * 768 + tid, acc);
        }
      }
      postw(fl, 0, (unsigned)(t + 1));
      // S10 (low half): x[0:128) = lw rows 0..127; 8 parts x 16 groups
      {
        int part = tid >> 7, j = tid & 127;
        const float4* xr = (const float4*)xcat;
        float a = 0.f;
#pragma unroll
        for (int g = 0; g < 16; ++g) {
          int gg = part * 16 + g;
          uint4 w = *(const uint4*)(wb + OLW + (size_t)gg * 2048 + j * 8);
          a += dot8(w, xr[gg * 2], xr[gg * 2 + 1]);
        }
        pt[part * 132 + j] = a;
      }
      __syncthreads();
      if (tid < 128) {
        float a = A.lb[tid];
#pragma unroll
        for (int q = 0; q < 8; ++q) a += pt[q * 132 + tid];
        xl[tid] = a;
        gst(ws + B_XLO(p) + b * 128 + tid, a);
      }
      postw(fl, 4, (unsigned)(t + 1));
      if (tid == 0) pollge<1>(fl, NB_PART + b, 0, (unsigned)(t + 1));
      __syncthreads();
      if (tid < 128) xl[128 + tid] = gld(ws + B_XH(p) + b * 128 + tid);
      __syncthreads();
      // S11 (low half): gate rows {0-127,256-383,512-639}
      {
        if (tid < 768) {
          int part = tid >= 384, ri = tid - part * 384;
          int row = ((ri >> 7) << 8) + (ri & 127);
          const float4* xr = (const float4*)xl;
          float a = 0.f;
#pragma unroll
          for (int g = 0; g < 16; ++g) {
            int gg = part * 16 + g;
            uint4 w = *(const uint4*)(wb + OG1I + (size_t)gg * 6144 + row * 8);
            a += dot8(w, xr[gg * 2], xr[gg * 2 + 1]);
          }
          pt[part * 384 + ri] = a;
        } else if (tid < 776) {
          pollge<1>(fl, NB_WH1 + (tid - 768), 0, (unsigned)(t + 1));
        }
        __syncthreads();
        if (tid < 384) {
          int row = ((tid >> 7) << 8) + (tid & 127);
          sgi[tid] = pt[tid] + pt[384 + tid] + A.g1bi[row];
          sgh[tid] = gld(ws + B_GH1(p) + b * 768 + row);
        }
        __syncthreads();
        if (tid < 128) {
          float r = sigm(sgi[tid] + sgh[tid]);
          float z = sigm(sgi[128 + tid] + sgh[128 + tid]);
          float n = tanhf(sgi[256 + tid] + r * sgh[256 + tid]);
          float hnew = (1.f - z) * n + z * h1l[tid];
          h1l[tid] = hnew;
          gst(ws + B_H1(p) + b * 256 + tid, hnew);
          float x2v = xl[tid] + hnew;
          x2l[tid] = x2v;
          gst(ws + B_X2LO(p) + b * 128 + tid, x2v);
        }
        postw(fl, 2, (unsigned)(t + 1));
        if (tid == 0) pollge<1>(fl, NB_PART + b, 1, (unsigned)(t + 1));
        __syncthreads();
        if (tid < 128) x2l[128 + tid] = gld(ws + B_X2H(p) + b * 128 + tid);
        __syncthreads();
      }
      // S12 (low half)
      {
        if (tid < 768) {
          int part = tid >= 384, ri = tid - part * 384;
          int row = ((ri >> 7) << 8) + (ri & 127);
          const float4* xr = (const float4*)x2l;
          float a = 0.f;
#pragma unroll
          for (int g = 0; g < 16; ++g) {
            int gg = part * 16 + g;
            uint4 w = *(const uint4*)(wb + OG2I + (size_t)gg * 6144 + row * 8);
            a += dot8(w, xr[gg * 2], xr[gg * 2 + 1]);
          }
          pt[part * 384 + ri] = a;
        } else if (tid < 776) {
          pollge<1>(fl, NB_WH2 + (tid - 768), 0, (unsigned)(t + 1));
        }
        __syncthreads();
        if (tid < 384) {
          int row = ((tid >> 7) << 8) + (tid & 127);
          sgi[tid] = pt[tid] + pt[384 + tid] + A.g2bi[row];
          sgh[tid] = gld(ws + B_GH2(p) + b * 768 + row);
        }
        __syncthreads();
        if (tid < 128) {
          float r = sigm(sgi[tid] + sgh[tid]);
          float z = sigm(sgi[128 + tid] + sgh[128 + tid]);
          float n = tanhf(sgi[256 + tid] + r * sgh[256 + tid]);
          float hnew = (1.f - z) * n + z * h2l[tid];
          h2l[tid] = hnew;
          gst(ws + B_H2(p) + b * 256 + tid, hnew);
          float x3v = x2l[tid] + hnew;
          x3l[tid] = x3v;
          gst(ws + B_X3LO(p) + b * 128 + tid, x3v);
        }
        postw(fl, 3, (unsigned)(t + 1));
        if (tid == 0) pollge<1>(fl, NB_PART + b, 2, (unsigned)(t + 1));
        __syncthreads();
        if (tid < 128) x3l[128 + tid] = gld(ws + B_X3H(p) + b * 128 + tid);
        __syncthreads();
      }
      // S13 (low half): proj rows 0..199; 4 parts x 8 groups
      if (tid < 800) {
        int part = tid / 200, j = tid - part * 200;
        const float4* xr = (const float4*)x3l;
        float a = 0.f;
#pragma unroll
        for (int g = 0; g < 8; ++g) {
          int gg = part * 8 + g;
          uint4 w = *(const uint4*)(wb + OPR + (size_t)gg * 3200 + j * 8);
          a += dot8(w, xr[gg * 2], xr[gg * 2 + 1]);
        }
        pt[part * 204 + j] = a;
      }
      __syncthreads();
      if (tid < 200) {
        float v = pt[tid] + pt[204 + tid] + pt[408 + tid] + pt[612 + tid] + A.prb[tid];
        fr[tid] = v;
        gst(A.dout + (size_t)b * 100000 + (tid / 5) * 1250 + t * 5 + (tid % 5), v);
      }
      __syncthreads();
    }
  } else if (blk < NB_GA) {
    // ---- GIC: gic(t) = awi[:, :768] @ ctx(t-1) ----
    int rb = blk - NB_GIC, bg = rb >> 4, jg = rb & 15;
    int B = bg * 16, R0 = jg * 48;
    float* cl = sm;  // [16][772]
    for (int t = 0; t < TDEC; ++t) {
      const int p = t & 1;
      if (tid < 16) pollge<4>(fl, bg * 16 + tid, 0, (unsigned)t);
      __syncthreads();
      for (int idx = tid; idx < 12288; idx += 1024) {
        int bb = idx / 768, k = idx - bb * 768;
        cl[bb * 772 + k] = gld(ws + B_CTX(p ^ 1) + (B + bb) * 768 + k);
      }
      __syncthreads();
      if (tid < 768) {
        int rr = tid >> 4, bb = tid & 15;
        int row = R0 + rr;
        const uint4* wr = (const uint4*)(wb + OAWI + (size_t)row * 896);
        const float4* xr = (const float4*)(cl + bb * 772);
        float a = 0.f;
#pragma unroll 16
        for (int k4 = 0; k4 < 96; ++k4) a += dot8(wr[k4], xr[2*k4], xr[2*k4+1]);
        gst(ws + B_GIC(p) + (B + bb) * 768 + row, a);
      }
      postw(fl, 0, (unsigned)(t + 1));
    }
  } else if (blk < NB_WH1) {
    // ---- GA: gh(t) = awh @ hatt(t-1) ----
    int rb = blk - NB_GA, bg = rb >> 2, jg = rb & 3;
    int B = bg * 16, R0 = jg * 192;
    float* hl = sm;  // [16][260]
    for (int t = 0; t < TDEC; ++t) {
      const int p = t & 1;
      if (tid < 16) pollge<4>(fl, bg * 16 + tid, 1, (unsigned)t);
      __syncthreads();
      for (int idx = tid; idx < 4096; idx += 1024) {
        int bb = idx >> 8, k = idx & 255;
        hl[bb * 260 + k] = gld(ws + B_HATT(p ^ 1) + (B + bb) * 256 + k);
      }
      __syncthreads();
#pragma unroll
      for (int pass = 0; pass < 3; ++pass) {
        int rr = pass * 64 + (tid >> 4), bb = tid & 15;
        int row = R0 + rr;
        const uint4* wr = (const uint4*)(wb + OAWH + (size_t)row * 256);
        const float4* xr = (const float4*)(hl + bb * 260);
        float a = 0.f;
#pragma unroll 16
        for (int k4 = 0; k4 < 32; ++k4) a += dot8(wr[k4], xr[2*k4], xr[2*k4+1]);
        gst(ws + B_GH(p) + (B + bb) * 768 + row, a);
      }
      postw(fl, 0, (unsigned)(t + 1));
    }
  } else if (blk < NB_PART) {
    // ---- WH1/WH2: gh{1,2}(t) = g{1,2}wh @ h{1,2}(t-1), all 64 b ----
    const int isW2 = (blk >= NB_WH2);
    const int w = blk - (isW2 ? NB_WH2 : NB_WH1);
    const unsigned OW = isW2 ? OG2H : OG1H;
    const float* bh = isW2 ? A.g2bh : A.g1bh;
    const int hOff0  = isW2 ? B_H2(0)  : B_H1(0);
    const int ghOff0 = isW2 ? B_GH2(0) : B_GH1(0);
    const int word = isW2 ? 3 : 2;
    const int pword = isW2 ? 2 : 1;
    const int R0 = w * 96;
    float* hl = sm;  // [64][260]
    for (int t = 0; t < TDEC; ++t) {
      const int p = t & 1;
      if (tid < 64) {
        pollge<4>(fl, tid, word, (unsigned)t);
        pollge<4>(fl, NB_PART + tid, pword, (unsigned)t);
      }
      __syncthreads();
      for (int idx = tid; idx < 16384; idx += 1024) {
        int bb = idx >> 8, k = idx & 255;
        hl[bb * 260 + k] = gld(ws + hOff0 + (p ^ 1) * 16384 + bb * 256 + k);
      }
      __syncthreads();
#pragma unroll
      for (int pass = 0; pass < 6; ++pass) {
        int o = pass * 1024 + tid;
        int bb = o & 63, lr = o >> 6;
        int row = R0 + lr;
        const uint4* wr = (const uint4*)(wb + OW + (size_t)row * 256);
        const float4* xr = (const float4*)(hl + bb * 260);
        float a = 0.f;
#pragma unroll 16
        for (int k4 = 0; k4 < 32; ++k4) a += dot8(wr[k4], xr[2*k4], xr[2*k4+1]);
        gst(ws + ghOff0 + p * 49152 + bb * 768 + row, a + bh[row]);
      }
      postw(fl, 0, (unsigned)(t + 1));
    }
  } else {
    // ========== PARTNER: high halves of S10-S13 for b = blk-160 ==========
    const int b = blk - NB_PART;
    float* xcat = sm;            // 1032
    float* xl   = sm + 1032;     // 256
    float* x2l  = sm + 1288;     // 256
    float* x3l  = sm + 1544;     // 256
    float* h1h  = sm + 1800;     // 128
    float* h2h  = sm + 1928;     // 128
    float* sgiP = sm + 2056;     // 384
    float* sghP = sm + 2440;     // 384
    float* pt   = sm + 2824;     // 1056
    if (tid < 128) { h1h[tid] = 0.f; h2h[tid] = 0.f; }
    __syncthreads();
    for (int t = 0; t < TDEC; ++t) {
      const int p = t & 1;
      // wait ctx + hatt
      if (tid == 0) pollge<1>(fl, b, 0, (unsigned)(t + 1));
      else if (tid == 1) pollge<1>(fl, b, 1, (unsigned)(t + 1));
      __syncthreads();
      if (tid < 768) xcat[tid] = gld(ws + B_CTX(p) + b * 768 + tid);
      else xcat[tid] = gld(ws + B_HATT(p) + b * 256 + (tid - 768));
      __syncthreads();
      // S10h: x[128:256) = lw rows 128..255
      {
        int part = tid >> 7, j = tid & 127;
        const float4* xr = (const float4*)xcat;
        float a = 0.f;
#pragma unroll
        for (int g = 0; g < 16; ++g) {
          int gg = part * 16 + g;
          uint4 w = *(const uint4*)(wb + OLW + (size_t)gg * 2048 + (128 + j) * 8);
          a += dot8(w, xr[gg * 2], xr[gg * 2 + 1]);
        }
        pt[part * 132 + j] = a;
      }
      __syncthreads();
      if (tid < 128) {
        float a = A.lb[128 + tid];
#pragma unroll
        for (int q = 0; q < 8; ++q) a += pt[q * 132 + tid];
        xl[128 + tid] = a;
        gst(ws + B_XH(p) + b * 128 + tid, a);
      }
      postw(fl, 0, (unsigned)(t + 1));
      if (tid == 0) pollge<1>(fl, b, 4, (unsigned)(t + 1));
      __syncthreads();
      if (tid < 128) xl[tid] = gld(ws + B_XLO(p) + b * 128 + tid);
      __syncthreads();
      // S11h: gate rows {128-255,384-511,640-767}
      {
        if (tid < 768) {
          int part = tid >= 384, ri = tid - part * 384;
          int row = ((ri >> 7) << 8) + 128 + (ri & 127);
          const float4* xr = (const float4*)xl;
          float a = 0.f;
#pragma unroll
          for (int g = 0; g < 16; ++g) {
            int gg = part * 16 + g;
            uint4 w = *(const uint4*)(wb + OG1I + (size_t)gg * 6144 + row * 8);
            a += dot8(w, xr[gg * 2], xr[gg * 2 + 1]);
          }
          pt[part * 384 + ri] = a;
        } else if (tid < 776) {
          pollge<1>(fl, NB_WH1 + (tid - 768), 0, (unsigned)(t + 1));
        }
        __syncthreads();
        if (tid < 384) {
          int row = ((tid >> 7) << 8) + 128 + (tid & 127);
          sgiP[tid] = pt[tid] + pt[384 + tid] + A.g1bi[row];
          sghP[tid] = gld(ws + B_GH1(p) + b * 768 + row);
        }
        __syncthreads();
        if (tid < 128) {
          float r = sigm(sgiP[tid] + sghP[tid]);
          float z = sigm(sgiP[128 + tid] + sghP[128 + tid]);
          float n = tanhf(sgiP[256 + tid] + r * sghP[256 + tid]);
          float hnew = (1.f - z) * n + z * h1h[tid];
          h1h[tid] = hnew;
          gst(ws + B_H1(p) + b * 256 + 128 + tid, hnew);
          float x2v = xl[128 + tid] + hnew;
          x2l[128 + tid] = x2v;
          gst(ws + B_X2H(p) + b * 128 + tid, x2v);
        }
        postw(fl, 1, (unsigned)(t + 1));
        if (tid == 0) pollge<1>(fl, b, 2, (unsigned)(t + 1));
        __syncthreads();
        if (tid < 128) x2l[tid] = gld(ws + B_X2LO(p) + b * 128 + tid);
        __syncthreads();
      }
      // S12h
      {
        if (tid < 768) {
          int part = tid >= 384, ri = tid - part * 384;
          int row = ((ri >> 7) << 8) + 128 + (ri & 127);
          const float4* xr = (const float4*)x2l;
          float a = 0.f;
#pragma unroll
          for (int g = 0; g < 16; ++g) {
            int gg = part * 16 + g;
            uint4 w = *(const uint4*)(wb + OG2I + (size_t)gg * 6144 + row * 8);
            a += dot8(w, xr[gg * 2], xr[gg * 2 + 1]);
          }
          pt[part * 384 + ri] = a;
        } else if (tid < 776) {
          pollge<1>(fl, NB_WH2 + (tid - 768), 0, (unsigned)(t + 1));
        }
        __syncthreads();
        if (tid < 384) {
          int row = ((tid >> 7) << 8) + 128 + (tid & 127);
          sgiP[tid] = pt[tid] + pt[384 + tid] + A.g2bi[row];
          sghP[tid] = gld(ws + B_GH2(p) + b * 768 + row);
        }
        __syncthreads();
        if (tid < 128) {
          float r = sigm(sgiP[tid] + sghP[tid]);
          float z = sigm(sgiP[128 + tid] + sghP[128 + tid]);
          float n = tanhf(sgiP[256 + tid] + r * sghP[256 + tid]);
          float hnew = (1.f - z) * n + z * h2h[tid];
          h2h[tid] = hnew;
          gst(ws + B_H2(p) + b * 256 + 128 + tid, hnew);
          float x3v = x2l[128 + tid] + hnew;
          x3l[128 + tid] = x3v;
          gst(ws + B_X3H(p) + b * 128 + tid, x3v);
        }
        postw(fl, 2, (unsigned)(t + 1));
        if (tid == 0) pollge<1>(fl, b, 3, (unsigned)(t + 1));
        __syncthreads();
        if (tid < 128) x3l[tid] = gld(ws + B_X3LO(p) + b * 128 + tid);
        __syncthreads();
      }
      // S13h: proj rows 200..399 -> fr_hi + dout
      if (tid < 800) {
        int part = tid / 200, j = tid - part * 200;
        const float4* xr = (const float4*)x3l;
        float a = 0.f;
#pragma unroll
        for (int g = 0; g < 8; ++g) {
          int gg = part * 8 + g;
          uint4 w = *(const uint4*)(wb + OPR + (size_t)gg * 3200 + (200 + j) * 8);
          a += dot8(w, xr[gg * 2], xr[gg * 2 + 1]);
        }
        pt[part * 204 + j] = a;
      }
      __syncthreads();
      if (tid < 200) {
        int row = 200 + tid;
        float v = pt[tid] + pt[204 + tid] + pt[408 + tid] + pt[612 + tid] + A.prb[row];
        gst(ws + B_FRH((t + 1) & 1) + b * 208 + tid, v);
        gst(A.dout + (size_t)b * 100000 + (row / 5) * 1250 + t * 5 + (row % 5), v);
      }
      postw(fl, 3, (unsigned)(t + 1));
    }
  }
}

// ---------------- host ----------------
extern "C" void kernel_launch(void* const* d_in, const int* in_sizes, int n_in,
                              void* d_out, int out_size, void* d_ws, size_t ws_size,
                              hipStream_t stream) {
  (void)in_sizes; (void)n_in; (void)out_size; (void)ws_size;
  KArgs A;
  A.enc  = (const float*)d_in[0];
  A.p1w  = (const float*)d_in[1];  A.p1b  = (const float*)d_in[2];
  A.p2w  = (const float*)d_in[3];  A.p2b  = (const float*)d_in[4];
  A.awi  = (const float*)d_in[5];  A.abi  = (const float*)d_in[6];
  A.awh  = (const float*)d_in[7];  A.abh  = (const float*)d_in[8];
  A.dWw  = (const float*)d_in[9];  A.dWb  = (const float*)d_in[10];
  A.dVw  = (const float*)d_in[11]; A.dFw  = (const float*)d_in[12];
  A.dUw  = (const float*)d_in[13]; A.dTw  = (const float*)d_in[14];
  A.dTb  = (const float*)d_in[15]; A.dvw  = (const float*)d_in[16];
  A.lw   = (const float*)d_in[17]; A.lb   = (const float*)d_in[18];
  A.g1wi = (const float*)d_in[19]; A.g1bi = (const float*)d_in[20];
  A.g1wh = (const float*)d_in[21]; A.g1bh = (const float*)d_in[22];
  A.g2wi = (const float*)d_in[23]; A.g2bi = (const float*)d_in[24];
  A.g2wh = (const float*)d_in[25]; A.g2bh = (const float*)d_in[26];
  A.prw  = (const float*)d_in[27]; A.prb  = (const float*)d_in[28];
  A.ws   = (float*)d_ws;
  A.dout = (float*)d_out;

  // beta-binomial prior pmf (n=10, a=0.1, b=0.9), flipped
  {
    double aP = 0.1, bP = 0.9;
    double logB0 = lgamma(aP) + lgamma(bP) - lgamma(aP + bP);
    double pm[11];
    for (int k = 0; k <= 10; ++k) {
      double logC = lgamma(11.0) - lgamma(k + 1.0) - lgamma(11.0 - k);
      double logBt = lgamma(k + aP) + lgamma(10.0 - k + bP) - lgamma(10.0 + aP + bP);
      pm[k] = exp(logC + logBt - logB0);
    }
    for (int k = 0; k < 11; ++k) A.pr.v[k] = (float)pm[10 - k];
  }

  CvtArgs C;
  // k8-interleaved (mode 1): {src, dst, N, K, KP, sstr, soff, mode}
  C.s[0]  = {A.p1w,  OP1,   256, 400, 416, 400, 0, 1};
  C.s[1]  = {A.p2w,  OP2,   128, 256, 256, 256, 0, 1};
  C.s[2]  = {A.awi,  OAWIP, 768, 128, 128, 896, 768, 1};
  C.s[3]  = {A.dWw,  ODW,   128, 256, 256, 256, 0, 1};
  C.s[4]  = {A.dVw,  ODV,   168, 128, 128, 128, 0, 1};
  C.s[5]  = {A.lw,   OLW,   256, 1024, 1024, 1024, 0, 1};
  C.s[6]  = {A.g1wi, OG1I,  768, 256, 256, 256, 0, 1};
  C.s[7]  = {A.g2wi, OG2I,  768, 256, 256, 256, 0, 1};
  C.s[8]  = {A.prw,  OPR,   400, 256, 256, 256, 0, 1};
  // row-major (mode 0): N*KP = element count
  C.s[9]  = {A.awi,  OAWI,  768, 896, 896, 896, 0, 0};
  C.s[10] = {A.awh,  OAWH,  768, 256, 256, 256, 0, 0};
  C.s[11] = {A.g1wh, OG1H,  768, 256, 256, 256, 0, 0};
  C.s[12] = {A.g2wh, OG2H,  768, 256, 256, 256, 0, 0};

  k_init<<<256, 256, 0, stream>>>((float*)d_ws);
  k_cvt<<<256, 256, 0, stream>>>(C, (unsigned short*)((float*)d_ws + CVT_OFF));
  k_decode<<<NBLK, 1024, 0, stream>>>(A);
}